// Round 5
// baseline (490.758 us; speedup 1.0000x reference)
//
#include <hip/hip_runtime.h>
#include <cmath>

#define Bb 2048
#define Nn 128
#define Dd 64
#define Hh 128

typedef __attribute__((ext_vector_type(8))) short short8;
typedef __attribute__((ext_vector_type(4))) float f32x4;

__device__ __forceinline__ void ld4(float* d, const float* s) {
  const float4 v = *(const float4*)s;
  d[0] = v.x; d[1] = v.y; d[2] = v.z; d[3] = v.w;
}
__device__ __forceinline__ void st4(float* d, const float* s) {
  *(float4*)d = make_float4(s[0], s[1], s[2], s[3]);
}

// Fast 2-way bf16 split: hi = round-half-up bf16, lo = truncated bf16 of
// residual; ~2^-17 rel total with the lo*lo MFMA term dropped.
__device__ __forceinline__ void splitf(float v, unsigned short& hi, unsigned short& lo) {
  const unsigned up = __float_as_uint(v) + 0x8000u;
  hi = (unsigned short)(up >> 16);
  const float hif = __uint_as_float(up & 0xffff0000u);
  lo = (unsigned short)(__float_as_uint(v - hif) >> 16);
}

// Branch-free exact-GELU via Abramowitz-Stegun 7.1.26 (|erf err| <= 1.5e-7).
__device__ __forceinline__ float gelu_exact(float v) {
  const float s  = fabsf(v) * 0.70710678118654752f;
  const float tt = __builtin_amdgcn_rcpf(fmaf(0.3275911f, s, 1.0f));
  float p = fmaf(tt, 1.061405429f, -1.453152027f);
  p = fmaf(tt, p, 1.421413741f);
  p = fmaf(tt, p, -0.284496736f);
  p = fmaf(tt, p, 0.254829592f);
  p = p * tt;
  const float E  = exp2f(s * s * -1.44269504088896f);
  const float er = fmaf(-p, E, 1.0f);
  const float es = copysignf(er, v);
  return v * fmaf(0.5f, es, 0.5f);
}

// ---------------------------------------------------------------------------
// k_prep (grid Nn): fold enc/dec, fragment-pack W1/Wfold hi/lo, pack
// b1/lng/lnb, and (blocks 0-2) fragment-pack conn[d] to bf16 (0/1 exact).
// ---------------------------------------------------------------------------
__global__ __launch_bounds__(256)
void k_prep(const float* __restrict__ W1, const float* __restrict__ b1,
            const float* __restrict__ lng, const float* __restrict__ lnb,
            const float* __restrict__ W2, const float* __restrict__ b2,
            const float* __restrict__ encW, const float* __restrict__ encb,
            const float* __restrict__ decW, const float* __restrict__ conn,
            unsigned short* __restrict__ W1pHi, unsigned short* __restrict__ W1pLo,
            unsigned short* __restrict__ WfpHi, unsigned short* __restrict__ WfpLo,
            float* __restrict__ bfold, float4* __restrict__ colpack,
            unsigned short* __restrict__ connP) {
  __shared__ float sm[26112];                  // 104.4 KB
  float* decS = sm;                            // [64][68]
  float* E2s  = sm + 4352;                     // [64][68]
  float* W2s  = sm + 8704;                     // [128][68]
  float* Wfs  = sm + 17408;                    // [128][68]
  float* W1s  = sm;                            // [64][132] overlays decS+E2s
  const int n = blockIdx.x, t = threadIdx.x;

  // phase 1: stage decW, W2[n]
  #pragma unroll
  for (int i = 0; i < 4; ++i) {
    const int fi = t + i * 256;
    *(float4*)&decS[(fi >> 4) * 68 + (fi & 15) * 4] = *(const float4*)(decW + fi * 4);
  }
  #pragma unroll
  for (int i = 0; i < 8; ++i) {
    const int fi = t + i * 256;
    *(float4*)&W2s[(fi >> 4) * 68 + (fi & 15) * 4] =
        *(const float4*)(W2 + (size_t)n * 8192 + fi * 4);
  }
  __syncthreads();

  // phase 2: E2 = encW @ decW
  {
    const int d = t >> 2, f0 = (t & 3) * 16;
    float acc[16];
    #pragma unroll
    for (int ff = 0; ff < 16; ++ff) acc[ff] = 0.f;
    for (int e = 0; e < 64; ++e) {
      const float a = encW[d * 64 + e];
      #pragma unroll
      for (int ff = 0; ff < 16; ++ff) acc[ff] += a * decS[e * 68 + f0 + ff];
    }
    #pragma unroll
    for (int q = 0; q < 4; ++q) st4(&E2s[d * 68 + f0 + q * 4], &acc[q * 4]);
  }
  __syncthreads();

  // phase 3: Wfs = W2s @ E2s; bfold; colpack
  {
    const int h = t >> 1, f0 = (t & 1) * 32;
    float acc[32];
    #pragma unroll
    for (int ff = 0; ff < 32; ++ff) acc[ff] = 0.f;
    for (int d2 = 0; d2 < 64; ++d2) {
      const float a = W2s[h * 68 + d2];
      #pragma unroll
      for (int q = 0; q < 8; ++q) {
        float e4[4]; ld4(e4, &E2s[d2 * 68 + f0 + q * 4]);
        #pragma unroll
        for (int r = 0; r < 4; ++r) acc[q * 4 + r] += a * e4[r];
      }
    }
    #pragma unroll
    for (int q = 0; q < 8; ++q) st4(&Wfs[h * 68 + f0 + q * 4], &acc[q * 4]);
  }
  if (t < 64) {
    float s = 0.f;
    for (int e = 0; e < 64; ++e) s += encb[e] * decS[e * 68 + t];
    for (int d2 = 0; d2 < 64; ++d2) s += b2[n * 64 + d2] * E2s[d2 * 68 + t];
    bfold[n * 64 + t] = s;
  }
  if (t < 128)
    colpack[n * 128 + t] =
        make_float4(b1[n * 128 + t], lng[n * 128 + t], lnb[n * 128 + t], 0.f);
  __syncthreads();

  // phase 4: pack Wfs -> Wfp; stage W1 -> W1s
  #pragma unroll
  for (int rep = 0; rep < 4; ++rep) {
    const int idx = rep * 256 + t;
    const int c = idx >> 8, kc = (idx >> 6) & 3, l = idx & 63;
    const int f = c * 16 + (l & 15), k0 = kc * 32 + (l >> 4) * 8;
    short8 vh, vl;
    #pragma unroll
    for (int j = 0; j < 8; ++j) {
      unsigned short hi, lo; splitf(Wfs[(k0 + j) * 68 + f], hi, lo);
      vh[j] = (short)hi; vl[j] = (short)lo;
    }
    const size_t o = (((size_t)n * 4 + c) * 4 + kc) * 512 + (size_t)l * 8;
    *(short8*)(WfpHi + o) = vh;
    *(short8*)(WfpLo + o) = vl;
  }
  #pragma unroll
  for (int i = 0; i < 8; ++i) {
    const int fi = t + i * 256;
    *(float4*)&W1s[(fi >> 5) * 132 + (fi & 31) * 4] =
        *(const float4*)(W1 + (size_t)n * 8192 + fi * 4);
  }
  __syncthreads();

  // phase 5: pack W1s -> W1p
  #pragma unroll
  for (int rep = 0; rep < 4; ++rep) {
    const int idx = rep * 256 + t;
    const int c = idx >> 7, c2 = (idx >> 6) & 1, l = idx & 63;
    const int col = c * 16 + (l & 15), k0 = c2 * 32 + (l >> 4) * 8;
    short8 vh, vl;
    #pragma unroll
    for (int j = 0; j < 8; ++j) {
      unsigned short hi, lo; splitf(W1s[(k0 + j) * 132 + col], hi, lo);
      vh[j] = (short)hi; vl[j] = (short)lo;
    }
    const size_t o = (((size_t)n * 8 + c) * 2 + c2) * 512 + (size_t)l * 8;
    *(short8*)(W1pHi + o) = vh;
    *(short8*)(W1pLo + o) = vl;
  }

  // phase 6 (blocks 0-2): fragment-pack conn[n] (A-frags, bf16-exact 0/1)
  if (n < 3) {
    #pragma unroll
    for (int rep = 0; rep < 8; ++rep) {
      const int slot = rep * 256 + t;            // 2048 lane-slots
      const int rt = slot >> 8, kc = (slot >> 6) & 3, ll = slot & 63;
      const int i = rt * 16 + (ll & 15), j0 = kc * 32 + (ll >> 4) * 8;
      const float* cp = conn + (size_t)n * 16384 + i * 128 + j0;
      float cv[8];
      ld4(cv, cp); ld4(cv + 4, cp + 4);
      short8 v;
      #pragma unroll
      for (int j = 0; j < 8; ++j)
        v[j] = (short)(__float_as_uint(cv[j]) >> 16);   // 0.0/1.0 exact
      *(short8*)(connP + (((size_t)(n * 8 + rt)) * 4 + kc) * 512 + (size_t)ll * 8) = v;
    }
  }
}

// ---------------------------------------------------------------------------
// Kernel A: mdP[b,frag] = pack( GELU(LN(x@W1+b1)) @ Wfold[n] + bfold[n] )
// SPLITIN: d=0 reads fp32 x and splits; else reads bf16 hi/lo planes.
// Output md is written B-fragment-packed u32(hi|lo) for k_conn.
// ---------------------------------------------------------------------------
template<bool SPLITIN>
__global__ __launch_bounds__(256)
void k_mlp(const float* __restrict__ xin, const unsigned short* __restrict__ xHi,
           const unsigned short* __restrict__ xLo,
           const unsigned short* __restrict__ W1pHi, const unsigned short* __restrict__ W1pLo,
           const float4* __restrict__ colpack,
           const unsigned short* __restrict__ WfpHi, const unsigned short* __restrict__ WfpLo,
           const float* __restrict__ bfold, unsigned* __restrict__ mdP) {
  __shared__ unsigned short HgHi[64 * 128];   // XOR-swizzled: idx ^= (row&7)<<3
  __shared__ unsigned short HgLo[64 * 128];

  const int t = threadIdx.x;
  const int w = t >> 6, l = t & 63;
  const int lr = l & 15, lg = l >> 4, kb = lg * 8;
  // XCD-bijective block swizzle: 4096 blocks, 8 XCDs -> 16 contiguous nodes/XCD
  const int wg = blockIdx.x;
  const int n  = (wg & 7) * 16 + ((wg >> 3) >> 5);
  const int b0 = ((wg >> 3) & 31) * 64;
  const int arow = w * 16 + lr;

  // ---- X A-fragments ----
  short8 ahi[2], alo[2];
  if (SPLITIN) {
    const float* xr = xin + ((size_t)(b0 + arow) * Nn + n) * Dd;
    #pragma unroll
    for (int c2 = 0; c2 < 2; ++c2) {
      const float4 p0 = *(const float4*)(xr + c2 * 32 + kb);
      const float4 p1 = *(const float4*)(xr + c2 * 32 + kb + 4);
      const float vv[8] = {p0.x, p0.y, p0.z, p0.w, p1.x, p1.y, p1.z, p1.w};
      #pragma unroll
      for (int j = 0; j < 8; ++j) {
        unsigned short hi, lo; splitf(vv[j], hi, lo);
        ahi[c2][j] = (short)hi; alo[c2][j] = (short)lo;
      }
    }
  } else {
    const unsigned short* xh = xHi + ((size_t)(b0 + arow) * Nn + n) * Dd;
    const unsigned short* xl = xLo + ((size_t)(b0 + arow) * Nn + n) * Dd;
    #pragma unroll
    for (int c2 = 0; c2 < 2; ++c2) {
      ahi[c2] = *(const short8*)(xh + c2 * 32 + kb);
      alo[c2] = *(const short8*)(xl + c2 * 32 + kb);
    }
  }

  // ---- per-column constants (b1, ln_g, ln_b) ----
  float4 cpv[8];
  #pragma unroll
  for (int c = 0; c < 8; ++c) cpv[c] = colpack[n * 128 + c * 16 + lr];

  // ---- GEMM1: h = x@W1 + b1 ----
  f32x4 acc[8];
  #pragma unroll
  for (int c = 0; c < 8; ++c) {
    const float bb = cpv[c].x;
    acc[c] = (f32x4){bb, bb, bb, bb};
  }
  {
    const unsigned short* wh = W1pHi + (size_t)n * 8192 + (size_t)l * 8;
    const unsigned short* wl = W1pLo + (size_t)n * 8192 + (size_t)l * 8;
    #pragma unroll
    for (int c = 0; c < 8; ++c) {
      #pragma unroll
      for (int c2 = 0; c2 < 2; ++c2) {
        const int fo = (c * 2 + c2) * 512;
        const short8 bh = *(const short8*)(wh + fo);
        const short8 bl = *(const short8*)(wl + fo);
        acc[c] = __builtin_amdgcn_mfma_f32_16x16x32_bf16(alo[c2], bh, acc[c], 0, 0, 0);
        acc[c] = __builtin_amdgcn_mfma_f32_16x16x32_bf16(ahi[c2], bl, acc[c], 0, 0, 0);
        acc[c] = __builtin_amdgcn_mfma_f32_16x16x32_bf16(ahi[c2], bh, acc[c], 0, 0, 0);
      }
    }
  }

  // ---- LayerNorm + GELU, split to bf16, write swizzled Hg ----
  {
    float mu[4], rs[4];
    #pragma unroll
    for (int r = 0; r < 4; ++r) {
      float sm = 0.f, sq = 0.f;
      #pragma unroll
      for (int c = 0; c < 8; ++c) { const float v = acc[c][r]; sm += v; sq += v * v; }
      #pragma unroll
      for (int msk = 1; msk < 16; msk <<= 1) {
        sm += __shfl_xor(sm, msk);
        sq += __shfl_xor(sq, msk);
      }
      mu[r] = sm * (1.f / Hh);
      const float var = sq * (1.f / Hh) - mu[r] * mu[r];
      rs[r] = rsqrtf(var + 1e-5f);
    }
    #pragma unroll
    for (int c = 0; c < 8; ++c) {
      const int col = c * 16 + lr;
      const float gv = cpv[c].y, bv = cpv[c].z;
      #pragma unroll
      for (int r = 0; r < 4; ++r) {
        const int row = w * 16 + lg * 4 + r;
        const float v = gelu_exact((acc[c][r] - mu[r]) * rs[r] * gv + bv);
        unsigned short hi, lo; splitf(v, hi, lo);
        const int idx = (row * Hh + col) ^ ((row & 7) << 3);
        HgHi[idx] = hi; HgLo[idx] = lo;
      }
    }
  }
  __syncthreads();

  // ---- GEMM2: md = Hg @ Wfold + bfold ----
  f32x4 acc2[4];
  #pragma unroll
  for (int c = 0; c < 4; ++c) {
    const float bb = bfold[n * Dd + c * 16 + lr];
    acc2[c] = (f32x4){bb, bb, bb, bb};
  }
  short8 a2h[4], a2l[4];
  #pragma unroll
  for (int kc = 0; kc < 4; ++kc) {
    const int idx = (arow * Hh + kc * 32 + kb) ^ ((arow & 7) << 3);
    a2h[kc] = *(const short8*)&HgHi[idx];
    a2l[kc] = *(const short8*)&HgLo[idx];
  }
  {
    const unsigned short* fh = WfpHi + (size_t)n * 8192 + (size_t)l * 8;
    const unsigned short* fl = WfpLo + (size_t)n * 8192 + (size_t)l * 8;
    #pragma unroll
    for (int c = 0; c < 4; ++c) {
      #pragma unroll
      for (int kc = 0; kc < 4; ++kc) {
        const int fo = (c * 4 + kc) * 512;
        const short8 bh = *(const short8*)(fh + fo);
        const short8 bl = *(const short8*)(fl + fo);
        acc2[c] = __builtin_amdgcn_mfma_f32_16x16x32_bf16(a2l[kc], bh, acc2[c], 0, 0, 0);
        acc2[c] = __builtin_amdgcn_mfma_f32_16x16x32_bf16(a2h[kc], bl, acc2[c], 0, 0, 0);
        acc2[c] = __builtin_amdgcn_mfma_f32_16x16x32_bf16(a2h[kc], bh, acc2[c], 0, 0, 0);
      }
    }
  }
  // ---- store md B-fragment-packed: addr = b*8192 + (n>>5)*2048 + c*512
  //      + ((n>>3&3)*16 + lr)*8 + (n&7);  u32 = (hi<<16)|lo ----
  {
    unsigned* mp = mdP + ((n >> 5) * 2048 + (((n >> 3) & 3) * 16 + lr) * 8 + (n & 7));
    #pragma unroll
    for (int c = 0; c < 4; ++c) {
      #pragma unroll
      for (int r = 0; r < 4; ++r) {
        const int b = b0 + w * 16 + lg * 4 + r;
        unsigned short hi, lo; splitf(acc2[c][r], hi, lo);
        mp[(size_t)b * 8192 + c * 512] = ((unsigned)hi << 16) | lo;
      }
    }
  }
}

// ---------------------------------------------------------------------------
// Kernel B (MFMA, no LDS): x[b] = conn @ md[b] + decb.
// A = conn fragments (bf16-exact, prepacked, L2-resident);
// B = mdP fragments (u32 hi|lo, coalesced dwordx4 loads).
// LAST: write fp32 to d_out; else write bf16 hi/lo planes (aliased in d_out).
// ---------------------------------------------------------------------------
template<bool LAST>
__global__ __launch_bounds__(256)
void k_conn(const unsigned* __restrict__ mdP, const unsigned short* __restrict__ connP,
            const float* __restrict__ decb, unsigned short* __restrict__ xHi,
            unsigned short* __restrict__ xLo, float* __restrict__ xout) {
  const int b = blockIdx.x, t = threadIdx.x;
  const int w = t >> 6, l = t & 63, lr = l & 15, lg = l >> 4;

  f32x4 acc[2][4];
  #pragma unroll
  for (int et = 0; et < 4; ++et) {
    const float dv = decb[et * 16 + lr];
    acc[0][et] = (f32x4){dv, dv, dv, dv};
    acc[1][et] = acc[0][et];
  }

  const unsigned* mb = mdP + (size_t)b * 8192;
  #pragma unroll
  for (int kc = 0; kc < 4; ++kc) {
    const short8 a0 = *(const short8*)(connP + ((size_t)(w * 2 + 0) * 4 + kc) * 512 + (size_t)l * 8);
    const short8 a1 = *(const short8*)(connP + ((size_t)(w * 2 + 1) * 4 + kc) * 512 + (size_t)l * 8);
    #pragma unroll
    for (int et = 0; et < 4; ++et) {
      const unsigned* bp = mb + ((kc * 4 + et) * 64 + l) * 8;
      unsigned u[8];
      *(uint4*)&u[0] = *(const uint4*)bp;
      *(uint4*)&u[4] = *(const uint4*)(bp + 4);
      short8 bh, bl;
      #pragma unroll
      for (int j = 0; j < 8; ++j) {
        bh[j] = (short)(u[j] >> 16);
        bl[j] = (short)(u[j] & 0xffffu);
      }
      acc[0][et] = __builtin_amdgcn_mfma_f32_16x16x32_bf16(a0, bh, acc[0][et], 0, 0, 0);
      acc[1][et] = __builtin_amdgcn_mfma_f32_16x16x32_bf16(a1, bh, acc[1][et], 0, 0, 0);
      acc[0][et] = __builtin_amdgcn_mfma_f32_16x16x32_bf16(a0, bl, acc[0][et], 0, 0, 0);
      acc[1][et] = __builtin_amdgcn_mfma_f32_16x16x32_bf16(a1, bl, acc[1][et], 0, 0, 0);
    }
  }

  #pragma unroll
  for (int rt = 0; rt < 2; ++rt) {
    #pragma unroll
    for (int et = 0; et < 4; ++et) {
      #pragma unroll
      for (int r = 0; r < 4; ++r) {
        const int i = w * 32 + rt * 16 + lg * 4 + r;
        const int e = et * 16 + lr;
        const size_t o = ((size_t)b * Nn + i) * Dd + e;
        if (LAST) {
          xout[o] = acc[rt][et][r];
        } else {
          unsigned short hi, lo; splitf(acc[rt][et][r], hi, lo);
          xHi[o] = hi; xLo[o] = lo;
        }
      }
    }
  }
}

extern "C" void kernel_launch(void* const* d_in, const int* in_sizes, int n_in,
                              void* d_out, int out_size, void* d_ws, size_t ws_size,
                              hipStream_t stream) {
  const float* x0   = (const float*)d_in[0];
  const float* W1   = (const float*)d_in[1];
  const float* b1   = (const float*)d_in[2];
  const float* lng  = (const float*)d_in[3];
  const float* lnb  = (const float*)d_in[4];
  const float* W2   = (const float*)d_in[5];
  const float* b2   = (const float*)d_in[6];
  const float* encW = (const float*)d_in[7];
  const float* encb = (const float*)d_in[8];
  const float* decW = (const float*)d_in[9];
  const float* decb = (const float*)d_in[10];
  const float* conn = (const float*)d_in[11];

  char* ws = (char*)d_ws;
  unsigned* mdP = (unsigned*)ws;                        // 64 MB
  size_t off = 64ull << 20;
  unsigned short* W1pHi = (unsigned short*)(ws + off); off += 2ull << 20;
  unsigned short* W1pLo = (unsigned short*)(ws + off); off += 2ull << 20;
  unsigned short* WfpHi = (unsigned short*)(ws + off); off += 2ull << 20;
  unsigned short* WfpLo = (unsigned short*)(ws + off); off += 2ull << 20;
  float* bfold    = (float*)(ws + off); off += 128 * 64 * 4;
  float4* colpack = (float4*)(ws + off); off += 128 * 128 * 16;
  unsigned short* connP = (unsigned short*)(ws + off); off += 3ull * 16384 * 2;

  // bf16 hi/lo planes for intermediate x, aliased into d_out (2*32MB = 64MB)
  unsigned short* xHi = (unsigned short*)d_out;
  unsigned short* xLo = xHi + (size_t)Bb * Nn * Dd;

  k_prep<<<Nn, 256, 0, stream>>>(W1, b1, lng, lnb, W2, b2, encW, encb, decW,
                                 conn, W1pHi, W1pLo, WfpHi, WfpLo, bfold,
                                 colpack, connP);

  k_mlp<true><<<4096, 256, 0, stream>>>(x0, nullptr, nullptr, W1pHi, W1pLo,
                                        colpack, WfpHi, WfpLo, bfold, mdP);
  k_conn<false><<<Bb, 256, 0, stream>>>(mdP, connP, decb, xHi, xLo, nullptr);

  k_mlp<false><<<4096, 256, 0, stream>>>(nullptr, xHi, xLo, W1pHi, W1pLo,
                                         colpack, WfpHi, WfpLo, bfold, mdP);
  k_conn<false><<<Bb, 256, 0, stream>>>(mdP, connP + 16384, decb, xHi, xLo, nullptr);

  k_mlp<false><<<4096, 256, 0, stream>>>(nullptr, xHi, xLo, W1pHi, W1pLo,
                                         colpack, WfpHi, WfpLo, bfold, mdP);
  k_conn<true><<<Bb, 256, 0, stream>>>(mdP, connP + 32768, decb, nullptr, nullptr,
                                       (float*)d_out);
}

// Round 6
// 272.064 us; speedup vs baseline: 1.8038x; 1.8038x over previous
//
#include <hip/hip_runtime.h>
#include <cmath>

#define Bb 2048
#define Nn 128
#define Dd 64
#define Hh 128

typedef __attribute__((ext_vector_type(8))) short short8;
typedef __attribute__((ext_vector_type(4))) float f32x4;

__device__ __forceinline__ void ld4(float* d, const float* s) {
  const float4 v = *(const float4*)s;
  d[0] = v.x; d[1] = v.y; d[2] = v.z; d[3] = v.w;
}
__device__ __forceinline__ void st4(float* d, const float* s) {
  *(float4*)d = make_float4(s[0], s[1], s[2], s[3]);
}

// Fast 2-way bf16 split: hi = round-half-up bf16, lo = truncated bf16 of
// residual; ~2^-17 rel total with the lo*lo MFMA term dropped.
__device__ __forceinline__ void splitf(float v, unsigned short& hi, unsigned short& lo) {
  const unsigned up = __float_as_uint(v) + 0x8000u;
  hi = (unsigned short)(up >> 16);
  const float hif = __uint_as_float(up & 0xffff0000u);
  lo = (unsigned short)(__float_as_uint(v - hif) >> 16);
}

// Branch-free exact-GELU via Abramowitz-Stegun 7.1.26 (|erf err| <= 1.5e-7).
__device__ __forceinline__ float gelu_exact(float v) {
  const float s  = fabsf(v) * 0.70710678118654752f;
  const float tt = __builtin_amdgcn_rcpf(fmaf(0.3275911f, s, 1.0f));
  float p = fmaf(tt, 1.061405429f, -1.453152027f);
  p = fmaf(tt, p, 1.421413741f);
  p = fmaf(tt, p, -0.284496736f);
  p = fmaf(tt, p, 0.254829592f);
  p = p * tt;
  const float E  = exp2f(s * s * -1.44269504088896f);
  const float er = fmaf(-p, E, 1.0f);
  const float es = copysignf(er, v);
  return v * fmaf(0.5f, es, 0.5f);
}

// ---------------------------------------------------------------------------
// k_prep (grid Nn): fold enc/dec, fragment-pack W1/Wfold hi/lo, pack
// b1/lng/lnb, and (blocks 0-2) fragment-pack conn[d] to bf16 (0/1 exact).
// ---------------------------------------------------------------------------
__global__ __launch_bounds__(256)
void k_prep(const float* __restrict__ W1, const float* __restrict__ b1,
            const float* __restrict__ lng, const float* __restrict__ lnb,
            const float* __restrict__ W2, const float* __restrict__ b2,
            const float* __restrict__ encW, const float* __restrict__ encb,
            const float* __restrict__ decW, const float* __restrict__ conn,
            unsigned short* __restrict__ W1pHi, unsigned short* __restrict__ W1pLo,
            unsigned short* __restrict__ WfpHi, unsigned short* __restrict__ WfpLo,
            float* __restrict__ bfold, float4* __restrict__ colpack,
            unsigned short* __restrict__ connP) {
  __shared__ float sm[26112];                  // 104.4 KB
  float* decS = sm;                            // [64][68]
  float* E2s  = sm + 4352;                     // [64][68]
  float* W2s  = sm + 8704;                     // [128][68]
  float* Wfs  = sm + 17408;                    // [128][68]
  float* W1s  = sm;                            // [64][132] overlays decS+E2s
  const int n = blockIdx.x, t = threadIdx.x;

  // phase 1: stage decW, W2[n]
  #pragma unroll
  for (int i = 0; i < 4; ++i) {
    const int fi = t + i * 256;
    *(float4*)&decS[(fi >> 4) * 68 + (fi & 15) * 4] = *(const float4*)(decW + fi * 4);
  }
  #pragma unroll
  for (int i = 0; i < 8; ++i) {
    const int fi = t + i * 256;
    *(float4*)&W2s[(fi >> 4) * 68 + (fi & 15) * 4] =
        *(const float4*)(W2 + (size_t)n * 8192 + fi * 4);
  }
  __syncthreads();

  // phase 2: E2 = encW @ decW
  {
    const int d = t >> 2, f0 = (t & 3) * 16;
    float acc[16];
    #pragma unroll
    for (int ff = 0; ff < 16; ++ff) acc[ff] = 0.f;
    for (int e = 0; e < 64; ++e) {
      const float a = encW[d * 64 + e];
      #pragma unroll
      for (int ff = 0; ff < 16; ++ff) acc[ff] += a * decS[e * 68 + f0 + ff];
    }
    #pragma unroll
    for (int q = 0; q < 4; ++q) st4(&E2s[d * 68 + f0 + q * 4], &acc[q * 4]);
  }
  __syncthreads();

  // phase 3: Wfs = W2s @ E2s; bfold; colpack
  {
    const int h = t >> 1, f0 = (t & 1) * 32;
    float acc[32];
    #pragma unroll
    for (int ff = 0; ff < 32; ++ff) acc[ff] = 0.f;
    for (int d2 = 0; d2 < 64; ++d2) {
      const float a = W2s[h * 68 + d2];
      #pragma unroll
      for (int q = 0; q < 8; ++q) {
        float e4[4]; ld4(e4, &E2s[d2 * 68 + f0 + q * 4]);
        #pragma unroll
        for (int r = 0; r < 4; ++r) acc[q * 4 + r] += a * e4[r];
      }
    }
    #pragma unroll
    for (int q = 0; q < 8; ++q) st4(&Wfs[h * 68 + f0 + q * 4], &acc[q * 4]);
  }
  if (t < 64) {
    float s = 0.f;
    for (int e = 0; e < 64; ++e) s += encb[e] * decS[e * 68 + t];
    for (int d2 = 0; d2 < 64; ++d2) s += b2[n * 64 + d2] * E2s[d2 * 68 + t];
    bfold[n * 64 + t] = s;
  }
  if (t < 128)
    colpack[n * 128 + t] =
        make_float4(b1[n * 128 + t], lng[n * 128 + t], lnb[n * 128 + t], 0.f);
  __syncthreads();

  // phase 4: pack Wfs -> Wfp; stage W1 -> W1s
  #pragma unroll
  for (int rep = 0; rep < 4; ++rep) {
    const int idx = rep * 256 + t;
    const int c = idx >> 8, kc = (idx >> 6) & 3, l = idx & 63;
    const int f = c * 16 + (l & 15), k0 = kc * 32 + (l >> 4) * 8;
    short8 vh, vl;
    #pragma unroll
    for (int j = 0; j < 8; ++j) {
      unsigned short hi, lo; splitf(Wfs[(k0 + j) * 68 + f], hi, lo);
      vh[j] = (short)hi; vl[j] = (short)lo;
    }
    const size_t o = (((size_t)n * 4 + c) * 4 + kc) * 512 + (size_t)l * 8;
    *(short8*)(WfpHi + o) = vh;
    *(short8*)(WfpLo + o) = vl;
  }
  #pragma unroll
  for (int i = 0; i < 8; ++i) {
    const int fi = t + i * 256;
    *(float4*)&W1s[(fi >> 5) * 132 + (fi & 31) * 4] =
        *(const float4*)(W1 + (size_t)n * 8192 + fi * 4);
  }
  __syncthreads();

  // phase 5: pack W1s -> W1p
  #pragma unroll
  for (int rep = 0; rep < 4; ++rep) {
    const int idx = rep * 256 + t;
    const int c = idx >> 7, c2 = (idx >> 6) & 1, l = idx & 63;
    const int col = c * 16 + (l & 15), k0 = c2 * 32 + (l >> 4) * 8;
    short8 vh, vl;
    #pragma unroll
    for (int j = 0; j < 8; ++j) {
      unsigned short hi, lo; splitf(W1s[(k0 + j) * 132 + col], hi, lo);
      vh[j] = (short)hi; vl[j] = (short)lo;
    }
    const size_t o = (((size_t)n * 8 + c) * 2 + c2) * 512 + (size_t)l * 8;
    *(short8*)(W1pHi + o) = vh;
    *(short8*)(W1pLo + o) = vl;
  }

  // phase 6 (blocks 0-2): fragment-pack conn[n] (A-frags, bf16-exact 0/1)
  if (n < 3) {
    #pragma unroll
    for (int rep = 0; rep < 8; ++rep) {
      const int slot = rep * 256 + t;            // 2048 lane-slots
      const int rt = slot >> 8, kc = (slot >> 6) & 3, ll = slot & 63;
      const int i = rt * 16 + (ll & 15), j0 = kc * 32 + (ll >> 4) * 8;
      const float* cp = conn + (size_t)n * 16384 + i * 128 + j0;
      float cv[8];
      ld4(cv, cp); ld4(cv + 4, cp + 4);
      short8 v;
      #pragma unroll
      for (int j = 0; j < 8; ++j)
        v[j] = (short)(__float_as_uint(cv[j]) >> 16);   // 0.0/1.0 exact
      *(short8*)(connP + (((size_t)(n * 8 + rt)) * 4 + kc) * 512 + (size_t)ll * 8) = v;
    }
  }
}

// ---------------------------------------------------------------------------
// Kernel A: mdP[b,n,f] = packU32( GELU(LN(x@W1+b1)) @ Wfold[n] + bfold[n] )
// Store is CONTIGUOUS (full 64B lines per 16-lane group) — the n->K transpose
// for k_conn happens in k_conn's LDS, not in the global store pattern.
// ---------------------------------------------------------------------------
template<bool SPLITIN>
__global__ __launch_bounds__(256)
void k_mlp(const float* __restrict__ xin, const unsigned short* __restrict__ xHi,
           const unsigned short* __restrict__ xLo,
           const unsigned short* __restrict__ W1pHi, const unsigned short* __restrict__ W1pLo,
           const float4* __restrict__ colpack,
           const unsigned short* __restrict__ WfpHi, const unsigned short* __restrict__ WfpLo,
           const float* __restrict__ bfold, unsigned* __restrict__ mdP) {
  __shared__ unsigned short HgHi[64 * 128];   // XOR-swizzled: idx ^= (row&7)<<3
  __shared__ unsigned short HgLo[64 * 128];

  const int t = threadIdx.x;
  const int w = t >> 6, l = t & 63;
  const int lr = l & 15, lg = l >> 4, kb = lg * 8;
  // XCD-bijective block swizzle: 4096 blocks, 8 XCDs -> 16 contiguous nodes/XCD
  const int wg = blockIdx.x;
  const int n  = (wg & 7) * 16 + ((wg >> 3) >> 5);
  const int b0 = ((wg >> 3) & 31) * 64;
  const int arow = w * 16 + lr;

  // ---- X A-fragments ----
  short8 ahi[2], alo[2];
  if (SPLITIN) {
    const float* xr = xin + ((size_t)(b0 + arow) * Nn + n) * Dd;
    #pragma unroll
    for (int c2 = 0; c2 < 2; ++c2) {
      const float4 p0 = *(const float4*)(xr + c2 * 32 + kb);
      const float4 p1 = *(const float4*)(xr + c2 * 32 + kb + 4);
      const float vv[8] = {p0.x, p0.y, p0.z, p0.w, p1.x, p1.y, p1.z, p1.w};
      #pragma unroll
      for (int j = 0; j < 8; ++j) {
        unsigned short hi, lo; splitf(vv[j], hi, lo);
        ahi[c2][j] = (short)hi; alo[c2][j] = (short)lo;
      }
    }
  } else {
    const unsigned short* xh = xHi + ((size_t)(b0 + arow) * Nn + n) * Dd;
    const unsigned short* xl = xLo + ((size_t)(b0 + arow) * Nn + n) * Dd;
    #pragma unroll
    for (int c2 = 0; c2 < 2; ++c2) {
      ahi[c2] = *(const short8*)(xh + c2 * 32 + kb);
      alo[c2] = *(const short8*)(xl + c2 * 32 + kb);
    }
  }

  // ---- per-column constants (b1, ln_g, ln_b) ----
  float4 cpv[8];
  #pragma unroll
  for (int c = 0; c < 8; ++c) cpv[c] = colpack[n * 128 + c * 16 + lr];

  // ---- GEMM1: h = x@W1 + b1 ----
  f32x4 acc[8];
  #pragma unroll
  for (int c = 0; c < 8; ++c) {
    const float bb = cpv[c].x;
    acc[c] = (f32x4){bb, bb, bb, bb};
  }
  {
    const unsigned short* wh = W1pHi + (size_t)n * 8192 + (size_t)l * 8;
    const unsigned short* wl = W1pLo + (size_t)n * 8192 + (size_t)l * 8;
    #pragma unroll
    for (int c = 0; c < 8; ++c) {
      #pragma unroll
      for (int c2 = 0; c2 < 2; ++c2) {
        const int fo = (c * 2 + c2) * 512;
        const short8 bh = *(const short8*)(wh + fo);
        const short8 bl = *(const short8*)(wl + fo);
        acc[c] = __builtin_amdgcn_mfma_f32_16x16x32_bf16(alo[c2], bh, acc[c], 0, 0, 0);
        acc[c] = __builtin_amdgcn_mfma_f32_16x16x32_bf16(ahi[c2], bl, acc[c], 0, 0, 0);
        acc[c] = __builtin_amdgcn_mfma_f32_16x16x32_bf16(ahi[c2], bh, acc[c], 0, 0, 0);
      }
    }
  }

  // ---- LayerNorm + GELU, split to bf16, write swizzled Hg ----
  {
    float mu[4], rs[4];
    #pragma unroll
    for (int r = 0; r < 4; ++r) {
      float sm = 0.f, sq = 0.f;
      #pragma unroll
      for (int c = 0; c < 8; ++c) { const float v = acc[c][r]; sm += v; sq += v * v; }
      #pragma unroll
      for (int msk = 1; msk < 16; msk <<= 1) {
        sm += __shfl_xor(sm, msk);
        sq += __shfl_xor(sq, msk);
      }
      mu[r] = sm * (1.f / Hh);
      const float var = sq * (1.f / Hh) - mu[r] * mu[r];
      rs[r] = rsqrtf(var + 1e-5f);
    }
    #pragma unroll
    for (int c = 0; c < 8; ++c) {
      const int col = c * 16 + lr;
      const float gv = cpv[c].y, bv = cpv[c].z;
      #pragma unroll
      for (int r = 0; r < 4; ++r) {
        const int row = w * 16 + lg * 4 + r;
        const float v = gelu_exact((acc[c][r] - mu[r]) * rs[r] * gv + bv);
        unsigned short hi, lo; splitf(v, hi, lo);
        const int idx = (row * Hh + col) ^ ((row & 7) << 3);
        HgHi[idx] = hi; HgLo[idx] = lo;
      }
    }
  }
  __syncthreads();

  // ---- GEMM2: md = Hg @ Wfold + bfold ----
  f32x4 acc2[4];
  #pragma unroll
  for (int c = 0; c < 4; ++c) {
    const float bb = bfold[n * Dd + c * 16 + lr];
    acc2[c] = (f32x4){bb, bb, bb, bb};
  }
  short8 a2h[4], a2l[4];
  #pragma unroll
  for (int kc = 0; kc < 4; ++kc) {
    const int idx = (arow * Hh + kc * 32 + kb) ^ ((arow & 7) << 3);
    a2h[kc] = *(const short8*)&HgHi[idx];
    a2l[kc] = *(const short8*)&HgLo[idx];
  }
  {
    const unsigned short* fh = WfpHi + (size_t)n * 8192 + (size_t)l * 8;
    const unsigned short* fl = WfpLo + (size_t)n * 8192 + (size_t)l * 8;
    #pragma unroll
    for (int c = 0; c < 4; ++c) {
      #pragma unroll
      for (int kc = 0; kc < 4; ++kc) {
        const int fo = (c * 4 + kc) * 512;
        const short8 bh = *(const short8*)(fh + fo);
        const short8 bl = *(const short8*)(fl + fo);
        acc2[c] = __builtin_amdgcn_mfma_f32_16x16x32_bf16(a2l[kc], bh, acc2[c], 0, 0, 0);
        acc2[c] = __builtin_amdgcn_mfma_f32_16x16x32_bf16(a2h[kc], bl, acc2[c], 0, 0, 0);
        acc2[c] = __builtin_amdgcn_mfma_f32_16x16x32_bf16(a2h[kc], bh, acc2[c], 0, 0, 0);
      }
    }
  }
  // ---- store md contiguous [b][n][f] as u32(hi|lo): 16 lanes = 64B lines ----
  #pragma unroll
  for (int c = 0; c < 4; ++c) {
    const int f = c * 16 + lr;
    #pragma unroll
    for (int r = 0; r < 4; ++r) {
      const int b = b0 + w * 16 + lg * 4 + r;
      unsigned short hi, lo; splitf(acc2[c][r], hi, lo);
      mdP[((size_t)b * Nn + n) * Dd + f] = ((unsigned)hi << 16) | lo;
    }
  }
}

// ---------------------------------------------------------------------------
// Kernel B (MFMA): x[b] = conn @ md[b] + decb.
// md[b] staged in LDS tl[j*65+e] (pad-65: staging writes AND fragment reads
// are exactly 2 lanes/bank = conflict-free). B-frags: 8x ds_read_b32 + unpack.
// A = conn fragments (bf16-exact, prepacked, L2-resident).
// LAST: write fp32 to d_out; else write bf16 hi/lo planes (aliased in d_out).
// ---------------------------------------------------------------------------
template<bool LAST>
__global__ __launch_bounds__(256)
void k_conn(const unsigned* __restrict__ mdP, const unsigned short* __restrict__ connP,
            const float* __restrict__ decb, unsigned short* __restrict__ xHi,
            unsigned short* __restrict__ xLo, float* __restrict__ xout) {
  __shared__ unsigned tl[128 * 65];            // 33.3 KB
  const int b = blockIdx.x, t = threadIdx.x;
  const int w = t >> 6, l = t & 63, lr = l & 15, lg = l >> 4;

  // stage md[b] transposed-addressable: tl[j*65 + e]
  const unsigned* mb = mdP + (size_t)b * (Nn * Dd);
  #pragma unroll
  for (int i = 0; i < 8; ++i) {
    const int fi = t + i * 256;                // uint4 index 0..2047
    const int j = fi >> 4, e0 = (fi & 15) * 4;
    const uint4 v = *(const uint4*)(mb + (size_t)fi * 4);
    unsigned* dp = &tl[j * 65 + e0];
    dp[0] = v.x; dp[1] = v.y; dp[2] = v.z; dp[3] = v.w;
  }
  __syncthreads();

  f32x4 acc[2][4];
  #pragma unroll
  for (int et = 0; et < 4; ++et) {
    const float dv = decb[et * 16 + lr];
    acc[0][et] = (f32x4){dv, dv, dv, dv};
    acc[1][et] = acc[0][et];
  }

  #pragma unroll
  for (int kc = 0; kc < 4; ++kc) {
    const short8 a0 = *(const short8*)(connP + ((size_t)(w * 2 + 0) * 4 + kc) * 512 + (size_t)l * 8);
    const short8 a1 = *(const short8*)(connP + ((size_t)(w * 2 + 1) * 4 + kc) * 512 + (size_t)l * 8);
    #pragma unroll
    for (int et = 0; et < 4; ++et) {
      const unsigned* tp = &tl[(kc * 32 + lg * 8) * 65 + et * 16 + lr];
      unsigned u[8];
      #pragma unroll
      for (int j = 0; j < 8; ++j) u[j] = tp[j * 65];
      short8 bh, bl;
      #pragma unroll
      for (int j = 0; j < 8; ++j) {
        bh[j] = (short)(u[j] >> 16);
        bl[j] = (short)(u[j] & 0xffffu);
      }
      acc[0][et] = __builtin_amdgcn_mfma_f32_16x16x32_bf16(a0, bh, acc[0][et], 0, 0, 0);
      acc[1][et] = __builtin_amdgcn_mfma_f32_16x16x32_bf16(a1, bh, acc[1][et], 0, 0, 0);
      acc[0][et] = __builtin_amdgcn_mfma_f32_16x16x32_bf16(a0, bl, acc[0][et], 0, 0, 0);
      acc[1][et] = __builtin_amdgcn_mfma_f32_16x16x32_bf16(a1, bl, acc[1][et], 0, 0, 0);
    }
  }

  #pragma unroll
  for (int rt = 0; rt < 2; ++rt) {
    #pragma unroll
    for (int et = 0; et < 4; ++et) {
      #pragma unroll
      for (int r = 0; r < 4; ++r) {
        const int i = w * 32 + rt * 16 + lg * 4 + r;
        const int e = et * 16 + lr;
        const size_t o = ((size_t)b * Nn + i) * Dd + e;
        if (LAST) {
          xout[o] = acc[rt][et][r];
        } else {
          unsigned short hi, lo; splitf(acc[rt][et][r], hi, lo);
          xHi[o] = hi; xLo[o] = lo;
        }
      }
    }
  }
}

extern "C" void kernel_launch(void* const* d_in, const int* in_sizes, int n_in,
                              void* d_out, int out_size, void* d_ws, size_t ws_size,
                              hipStream_t stream) {
  const float* x0   = (const float*)d_in[0];
  const float* W1   = (const float*)d_in[1];
  const float* b1   = (const float*)d_in[2];
  const float* lng  = (const float*)d_in[3];
  const float* lnb  = (const float*)d_in[4];
  const float* W2   = (const float*)d_in[5];
  const float* b2   = (const float*)d_in[6];
  const float* encW = (const float*)d_in[7];
  const float* encb = (const float*)d_in[8];
  const float* decW = (const float*)d_in[9];
  const float* decb = (const float*)d_in[10];
  const float* conn = (const float*)d_in[11];

  char* ws = (char*)d_ws;
  unsigned* mdP = (unsigned*)ws;                        // 64 MB
  size_t off = 64ull << 20;
  unsigned short* W1pHi = (unsigned short*)(ws + off); off += 2ull << 20;
  unsigned short* W1pLo = (unsigned short*)(ws + off); off += 2ull << 20;
  unsigned short* WfpHi = (unsigned short*)(ws + off); off += 2ull << 20;
  unsigned short* WfpLo = (unsigned short*)(ws + off); off += 2ull << 20;
  float* bfold    = (float*)(ws + off); off += 128 * 64 * 4;
  float4* colpack = (float4*)(ws + off); off += 128 * 128 * 16;
  unsigned short* connP = (unsigned short*)(ws + off); off += 3ull * 16384 * 2;

  // bf16 hi/lo planes for intermediate x, aliased into d_out (2*32MB = 64MB)
  unsigned short* xHi = (unsigned short*)d_out;
  unsigned short* xLo = xHi + (size_t)Bb * Nn * Dd;

  k_prep<<<Nn, 256, 0, stream>>>(W1, b1, lng, lnb, W2, b2, encW, encb, decW,
                                 conn, W1pHi, W1pLo, WfpHi, WfpLo, bfold,
                                 colpack, connP);

  k_mlp<true><<<4096, 256, 0, stream>>>(x0, nullptr, nullptr, W1pHi, W1pLo,
                                        colpack, WfpHi, WfpLo, bfold, mdP);
  k_conn<false><<<Bb, 256, 0, stream>>>(mdP, connP, decb, xHi, xLo, nullptr);

  k_mlp<false><<<4096, 256, 0, stream>>>(nullptr, xHi, xLo, W1pHi, W1pLo,
                                         colpack, WfpHi, WfpLo, bfold, mdP);
  k_conn<false><<<Bb, 256, 0, stream>>>(mdP, connP + 16384, decb, xHi, xLo, nullptr);

  k_mlp<false><<<4096, 256, 0, stream>>>(nullptr, xHi, xLo, W1pHi, W1pLo,
                                         colpack, WfpHi, WfpLo, bfold, mdP);
  k_conn<true><<<Bb, 256, 0, stream>>>(mdP, connP + 32768, decb, nullptr, nullptr,
                                       (float*)d_out);
}